// Round 17
// baseline (198.354 us; speedup 1.0000x reference)
//
#include <hip/hip_runtime.h>
#include <stdint.h>

typedef float f32x4 __attribute__((ext_vector_type(4)));
typedef short s16x8 __attribute__((ext_vector_type(8)));

// N=16, C=256, H=32, W=32, K=4096, M = N*H*W = 16384
// d_out layout (floats): quant[4194304] | code[16384] | logit[67108864] | v[1048576]
#define QUANT_OFF 0
#define CODE_OFF  4194304
#define LOGIT_OFF 4210688
#define V_OFF     71319552

// logit std ~= 0.0625 (codebook prescaled by 1/sqrt(C)); bf16-path absmax err 0.00195.
// Margin must exceed 2*err (0.0039); use 1/128 for 2x headroom.
#define ARGMAX_MARGIN 0.0078125f

__device__ __forceinline__ unsigned short f2bf(float f) {
  unsigned int u = __float_as_uint(f);
  u = u + 0x7fffu + ((u >> 16) & 1u);   // RNE
  return (unsigned short)(u >> 16);
}

__device__ __forceinline__ void load_lds16(const void* g, void* l) {
  __builtin_amdgcn_global_load_lds(
      (const __attribute__((address_space(1))) unsigned int*)g,
      (__attribute__((address_space(3))) unsigned int*)l, 16, 0, 0);
}

// ---------------- K1: fp32 VALU GEMMs, 128x128 tiles, 8x8 per thread ----------------
// blocks 0..63: k = cb@wk^T | 64..127: v = cb@wv^T | 128..383: q = x@wq^T.
// 2 FLOP per LDS byte (vs 1 before): 16 b128 reads per 256 FMAs per kc.
// BK=16 double-buffered, one __syncthreads per K-step, global_load_lds w=16.
// Swizzle SWZ4(x) = (x^(x>>3))&3 spreads stride-8 row reads across bank quads.
#define SWZ4(x) (((x) ^ ((x) >> 3)) & 3)
__global__ __launch_bounds__(256) void kvq_kernel(
    const float* __restrict__ latent, const float* __restrict__ wq,
    const float* __restrict__ cb, const float* __restrict__ wk, const float* __restrict__ wv,
    float* __restrict__ qf, unsigned short* __restrict__ qh,
    float* __restrict__ kf, unsigned short* __restrict__ kh, float* __restrict__ vout)
{
  __shared__ __align__(16) float A_s[2][2048];   // q: [k 16][row 128]; kv: [row 128][k 16] swz
  __shared__ __align__(16) float B_s[2][2048];   // [col 128][k 16] swz
  const int t = threadIdx.x;
  const int bid = blockIdx.x;
  const int tx = t & 15;
  const int ry = t >> 4;  // 0..15

  if (bid >= 128) {
    // ---------------- q path: 256 blocks (128 row-tiles x 2 col-tiles) ----------------
    const int qb = bid - 128;
    const int rowBase = (qb >> 1) * 128;
    const int colBase = (qb & 1) * 128;
    const int n = rowBase >> 10;
    const int hw0 = rowBase & 1023;
    float acc[8][8] = {};

    // A: [k][row] linear (latent's 16B = 4 consecutive rows at one k — no transpose).
    // B: [col][k] with XOR-swizzled source k-quad.
    #define QSTAGE(B, KT) do {                                                          \
      _Pragma("unroll")                                                                 \
      for (int it = 0; it < 2; ++it) {                                                  \
        int c = it * 256 + t;                                                           \
        int kk = c >> 5, rq = c & 31;                                                   \
        load_lds16(latent + ((size_t)(n * 256 + (KT) * 16 + kk) * 1024 + hw0 + rq * 4), \
                   &A_s[B][c * 4]);                                                     \
        int col = c >> 2, ls = c & 3;                                                   \
        int sk = ls ^ SWZ4(col);                                                        \
        load_lds16(wq + ((size_t)(colBase + col) * 256 + (KT) * 16 + sk * 4),           \
                   &B_s[B][c * 4]);                                                     \
      } } while (0)

    QSTAGE(0, 0);
    #pragma unroll 1
    for (int kt = 0; kt < 16; ++kt) {
      const int buf = kt & 1;
      __syncthreads();                      // drains buf's loads; fences prev reads
      if (kt < 15) QSTAGE(buf ^ 1, kt + 1); // prefetch flies under FMAs
      const float* As = A_s[buf];
      const float* Bs = B_s[buf];
      #pragma unroll
      for (int kc = 0; kc < 4; ++kc) {
        f32x4 alo[4], ahi[4], b[8];
        #pragma unroll
        for (int k4 = 0; k4 < 4; ++k4) {
          alo[k4] = *(const f32x4*)&As[(kc * 4 + k4) * 128 + ry * 8];
          ahi[k4] = *(const f32x4*)&As[(kc * 4 + k4) * 128 + ry * 8 + 4];
        }
        #pragma unroll
        for (int j = 0; j < 8; ++j) {
          const int col = tx + 16 * j;
          b[j] = *(const f32x4*)&Bs[col * 16 + (kc ^ SWZ4(col)) * 4];
        }
        #pragma unroll
        for (int k4 = 0; k4 < 4; ++k4)
          #pragma unroll
          for (int i = 0; i < 8; ++i) {
            const float av = (i < 4) ? alo[k4][i] : ahi[k4][i - 4];
            #pragma unroll
            for (int j = 0; j < 8; ++j)
              acc[i][j] = fmaf(av, b[j][k4], acc[i][j]);
          }
      }
    }
    #undef QSTAGE
    #pragma unroll
    for (int i = 0; i < 8; ++i) {
      const int r = rowBase + ry * 8 + i;
      #pragma unroll
      for (int j = 0; j < 8; ++j) {
        const int c = colBase + tx + 16 * j;
        qf[(size_t)r * 256 + c] = acc[i][j];
        qh[(size_t)r * 256 + c] = f2bf(acc[i][j] * 0.0625f);
      }
    }
  } else {
    // ---------------- k / v paths: 64 blocks each (32 row-tiles x 2 col-tiles) ----------------
    const bool isV = bid >= 64;
    const int kb = bid & 63;
    const int rowBase = (kb >> 1) * 128;
    const int colBase = (kb & 1) * 128;
    const float* W = isV ? wv : wk;
    float acc[8][8] = {};

    // A: [row][k] swz (cb is k-contiguous per row). B: [col][k] swz.
    #define KSTAGE(B, KT) do {                                                          \
      _Pragma("unroll")                                                                 \
      for (int it = 0; it < 2; ++it) {                                                  \
        int c = it * 256 + t;                                                           \
        int rw = c >> 2, ls = c & 3;                                                    \
        int sk = ls ^ SWZ4(rw);                                                         \
        load_lds16(cb + ((size_t)(rowBase + rw) * 256 + (KT) * 16 + sk * 4),            \
                   &A_s[B][c * 4]);                                                     \
        load_lds16(W  + ((size_t)(colBase + rw) * 256 + (KT) * 16 + sk * 4),            \
                   &B_s[B][c * 4]);                                                     \
      } } while (0)

    KSTAGE(0, 0);
    #pragma unroll 1
    for (int kt = 0; kt < 16; ++kt) {
      const int buf = kt & 1;
      __syncthreads();
      if (kt < 15) KSTAGE(buf ^ 1, kt + 1);
      const float* As = A_s[buf];
      const float* Bs = B_s[buf];
      #pragma unroll
      for (int kc = 0; kc < 4; ++kc) {
        f32x4 a[8], b[8];
        #pragma unroll
        for (int i = 0; i < 8; ++i) {
          const int row = ry * 8 + i;
          a[i] = *(const f32x4*)&As[row * 16 + (kc ^ SWZ4(row)) * 4];
        }
        #pragma unroll
        for (int j = 0; j < 8; ++j) {
          const int col = tx + 16 * j;
          b[j] = *(const f32x4*)&Bs[col * 16 + (kc ^ SWZ4(col)) * 4];
        }
        #pragma unroll
        for (int i = 0; i < 8; ++i)
          #pragma unroll
          for (int j = 0; j < 8; ++j) {
            acc[i][j] = fmaf(a[i].x, b[j].x, acc[i][j]);
            acc[i][j] = fmaf(a[i].y, b[j].y, acc[i][j]);
            acc[i][j] = fmaf(a[i].z, b[j].z, acc[i][j]);
            acc[i][j] = fmaf(a[i].w, b[j].w, acc[i][j]);
          }
      }
    }
    #undef KSTAGE
    #pragma unroll
    for (int i = 0; i < 8; ++i) {
      const int r = rowBase + ry * 8 + i;
      #pragma unroll
      for (int j = 0; j < 8; ++j) {
        const int c = colBase + tx + 16 * j;
        if (isV) {
          vout[(size_t)r * 256 + c] = acc[i][j];
        } else {
          kf[(size_t)r * 256 + c] = acc[i][j];
          kh[(size_t)r * 256 + c] = f2bf(acc[i][j]);
        }
      }
    }
  }
}

// ---------------- K2: logit = qh @ kh^T (bf16 MFMA) + fused blockmax ----------------
// Round-10 proven structure verbatim.
__global__ __launch_bounds__(256) void logit_gemm(
    const unsigned short* __restrict__ qh, const unsigned short* __restrict__ kh,
    float* __restrict__ out, float* __restrict__ pmax)
{
  __shared__ short AsBuf[2][128 * 32];
  __shared__ short BsBuf[2][128 * 32];
  __shared__ float Pm[128][2];
  const int t = threadIdx.x;
  const int bid = blockIdx.x;
  const int wg = (bid & 7) * 512 + (bid >> 3);  // XCD-chunked swizzle (4096 % 8 == 0)
  const int aRow0 = (wg >> 5) * 128;            // M block
  const int bRow0 = (wg & 31) * 128;            // N block
  const int lane = t & 63, wid = t >> 6;
  const int wr = wid >> 1, wc = wid & 1;
  f32x4 acc[4][4];
  #pragma unroll
  for (int m = 0; m < 4; ++m)
    #pragma unroll
    for (int n = 0; n < 4; ++n) { acc[m][n].x = 0.f; acc[m][n].y = 0.f; acc[m][n].z = 0.f; acc[m][n].w = 0.f; }

  const short* qs = (const short*)qh;
  const short* ks = (const short*)kh;

  #define STAGE32(AB, BB, KT) do {                                          \
    _Pragma("unroll")                                                       \
    for (int ci = 0; ci < 2; ++ci) {                                        \
      int c = ci * 256 + t;                                                 \
      int row = c >> 2;                                                     \
      int slot = (c & 3) ^ (row & 3);                                       \
      int koff = (KT) * 32 + slot * 8;                                      \
      load_lds16(qs + (size_t)(aRow0 + row) * 256 + koff, (AB) + c * 8);    \
      load_lds16(ks + (size_t)(bRow0 + row) * 256 + koff, (BB) + c * 8);    \
    } } while (0)

  STAGE32(AsBuf[0], BsBuf[0], 0);
  #pragma unroll
  for (int kt = 0; kt < 8; ++kt) {
    const int buf = kt & 1;
    __syncthreads();                       // drains buf's loads; fences prev reads of buf^1
    if (kt < 7) STAGE32(AsBuf[buf ^ 1], BsBuf[buf ^ 1], kt + 1);
    const short* As = AsBuf[buf];
    const short* Bs = BsBuf[buf];
    s16x8 af[4], bfr[4];
    #pragma unroll
    for (int m = 0; m < 4; ++m) {
      int row = wr * 64 + m * 16 + (lane & 15);
      int slot = (lane >> 4) ^ (row & 3);
      af[m] = *(const s16x8*)(As + row * 32 + slot * 8);
    }
    #pragma unroll
    for (int n = 0; n < 4; ++n) {
      int row = wc * 64 + n * 16 + (lane & 15);
      int slot = (lane >> 4) ^ (row & 3);
      bfr[n] = *(const s16x8*)(Bs + row * 32 + slot * 8);
    }
    #pragma unroll
    for (int m = 0; m < 4; ++m)
      #pragma unroll
      for (int n = 0; n < 4; ++n)
        acc[m][n] = __builtin_amdgcn_mfma_f32_16x16x32_bf16(af[m], bfr[n], acc[m][n], 0, 0, 0);
  }
  #undef STAGE32

  // fused blockmax: per (row, this 128-col block) max, into Pm then pmax
  #pragma unroll
  for (int m = 0; m < 4; ++m)
    #pragma unroll
    for (int j = 0; j < 4; ++j) {
      float bm = fmaxf(fmaxf(acc[m][0][j], acc[m][1][j]),
                       fmaxf(acc[m][2][j], acc[m][3][j]));
      #pragma unroll
      for (int off = 1; off < 16; off <<= 1) bm = fmaxf(bm, __shfl_xor(bm, off));
      if ((lane & 15) == 0) Pm[wr * 64 + m * 16 + (lane >> 4) * 4 + j][wc] = bm;
    }
  // logit store (proven scalar epilogue — L2 merges the 64B segments)
  const int colLane = lane & 15, rowQuad = (lane >> 4) * 4;
  #pragma unroll
  for (int m = 0; m < 4; ++m)
    #pragma unroll
    for (int n = 0; n < 4; ++n) {
      int row = aRow0 + wr * 64 + m * 16 + rowQuad;
      int col = bRow0 + wc * 64 + n * 16 + colLane;
      #pragma unroll
      for (int j = 0; j < 4; ++j)
        out[(size_t)(row + j) * 4096 + col] = acc[m][n][j];
    }
  __syncthreads();
  if (t < 128) pmax[(size_t)(aRow0 + t) * 32 + (bRow0 >> 7)] = fmaxf(Pm[t][0], Pm[t][1]);
}

// ---------------- K3: finalize — single-candidate fast path + exact recheck fallback ----------------
__global__ __launch_bounds__(1024) void finalize_kernel(
    const float* __restrict__ logit, const float* __restrict__ pmax,
    const float* __restrict__ qf, const float* __restrict__ kf,
    const float* __restrict__ vout, float* __restrict__ quant, float* __restrict__ code)
{
  __shared__ __align__(16) float Vs[32][260];
  __shared__ int idxArr[32];
  const int t = threadIdx.x, wave = t >> 6, lane = t & 63;
  const int nh = blockIdx.x, n = nh >> 5, h = nh & 31;
  for (int ri = 0; ri < 2; ++ri) {
    const int w = wave * 2 + ri;
    const size_t r = (size_t)nh * 32 + w;
    float pv = -3e38f;
    if (lane < 32) pv = pmax[r * 32 + lane];
    float gmax = pv;
    #pragma unroll
    for (int off = 32; off; off >>= 1) gmax = fmaxf(gmax, __shfl_xor(gmax, off));
    const float thr = gmax - ARGMAX_MARGIN;
    const unsigned long long bmAll = __ballot(pv >= thr);  // candidate 128-col blocks
    int tot = 0, firstJ = 0x7fffffff;
    {
      unsigned long long bm = bmAll;
      #pragma unroll 1
      while (bm) {
        const int nb = __ffsll(bm) - 1; bm &= bm - 1;
        const float2 lv = *(const float2*)&logit[r * 4096 + nb * 128 + lane * 2];
        unsigned long long c0 = __ballot(lv.x >= thr);
        unsigned long long c1 = __ballot(lv.y >= thr);
        tot += __popcll(c0) + __popcll(c1);
        if (firstJ == 0x7fffffff && (c0 | c1)) {
          int j0 = c0 ? nb * 128 + 2 * (__ffsll(c0) - 1)     : 0x7fffffff;
          int j1 = c1 ? nb * 128 + 2 * (__ffsll(c1) - 1) + 1 : 0x7fffffff;
          firstJ = j0 < j1 ? j0 : j1;
        }
      }
    }
    int bestJ = firstJ;
    if (tot > 1) {     // slow path: exact f64 recheck of every candidate
      const f32x4 qv = ((const f32x4*)(qf + r * 256))[lane];
      float bestV = -3e38f; bestJ = 0x7fffffff;
      unsigned long long bm = bmAll;
      #pragma unroll 1
      while (bm) {
        const int nb = __ffsll(bm) - 1; bm &= bm - 1;
        const float2 lv = *(const float2*)&logit[r * 4096 + nb * 128 + lane * 2];
        unsigned long long c0 = __ballot(lv.x >= thr);
        unsigned long long c1 = __ballot(lv.y >= thr);
        #pragma unroll 1
        for (int half = 0; half < 2; ++half) {
          unsigned long long mm = half ? c1 : c0;
          #pragma unroll 1
          while (mm) {
            const int L = __ffsll(mm) - 1; mm &= mm - 1;
            const int j = nb * 128 + L * 2 + half;
            const f32x4 kv = ((const f32x4*)(kf + (size_t)j * 256))[lane];
            double s = (double)qv.x * kv.x + (double)qv.y * kv.y
                     + (double)qv.z * kv.z + (double)qv.w * kv.w;
            #pragma unroll
            for (int off = 32; off; off >>= 1) s += __shfl_xor(s, off);
            const float val = (float)(s * 0.0625);
            if (val > bestV || (val == bestV && j < bestJ)) { bestV = val; bestJ = j; }
          }
        }
      }
    }
    if (lane == 0) idxArr[w] = bestJ;
  }
  __syncthreads();
  for (int ri = 0; ri < 2; ++ri) {
    const int w2 = wave * 2 + ri;
    const int idx = idxArr[w2];
    const f32x4 vv = ((const f32x4*)(vout + (size_t)idx * 256))[lane];
    *(f32x4*)&Vs[w2][lane * 4] = vv;
  }
  __syncthreads();
  const int wcol = t & 31, cg = t >> 5;
  #pragma unroll
  for (int cc = 0; cc < 8; ++cc) {
    const int c = cg * 8 + cc;
    quant[(((size_t)n * 256 + c) * 32 + h) * 32 + wcol] = Vs[wcol][c];
  }
  if (t < 32) code[nh * 32 + t] = (float)(idxArr[t] & 255);
}

extern "C" void kernel_launch(void* const* d_in, const int* in_sizes, int n_in,
                              void* d_out, int out_size, void* d_ws, size_t ws_size,
                              hipStream_t stream) {
  (void)in_sizes; (void)n_in; (void)out_size; (void)ws_size;
  const float* latent = (const float*)d_in[0];
  const float* cb     = (const float*)d_in[1];
  const float* wq     = (const float*)d_in[2];
  const float* wk     = (const float*)d_in[3];
  const float* wv     = (const float*)d_in[4];

  float* out   = (float*)d_out;
  float* quant = out + QUANT_OFF;
  float* code  = out + CODE_OFF;
  float* logit = out + LOGIT_OFF;
  float* vout  = out + V_OFF;

  char* ws = (char*)d_ws;
  float*          qf   = (float*)(ws + 0);                 // 16 MB
  float*          kf   = (float*)(ws + 16777216);          // 4 MB
  unsigned short* qh   = (unsigned short*)(ws + 20971520); // 8 MB
  unsigned short* kh   = (unsigned short*)(ws + 29360128); // 2 MB
  float*          pmax = (float*)(ws + 31457280);          // 2 MB (16384 x 32), ends at 32 MB

  kvq_kernel<<<384, 256, 0, stream>>>(latent, wq, cb, wk, wv, qf, qh, kf, kh, vout);
  logit_gemm<<<4096, 256, 0, stream>>>(qh, kh, logit, pmax);
  finalize_kernel<<<512, 1024, 0, stream>>>(logit, pmax, qf, kf, vout, quant, code);
}